// Round 2
// baseline (198.377 us; speedup 1.0000x reference)
//
#include <hip/hip_runtime.h>
#include <math.h>

// FSQuantizer fused pipeline v2 for MI355X.
// z (32,512,4096) f32, E=4, LEVELS={8,5,5,5}. Out: zhat f32 + commit + perplexity.
//
// P1: read z once (float4), c-split partial h/g (f32), z^2 / z.b_out stats, Gram (block 511).
// P2: combine c-split partials (f64), + b_in, BN block stats.
// P3: redundant per-block const reduce, f64 quantize, histogram, commit partials,
//     float4 zhat writes.
// P4: finalize commit + perplexity.

namespace {
constexpr int Cv = 512, Tv = 4096, Bv = 32;
constexpr int Nv = Bv * Tv;                       // 131072 rows
constexpr long long TOTv = (long long)Nv * Cv;    // 67108864
constexpr int CS = 4;                             // c splits
constexpr int CL = Cv / CS;                       // 128
constexpr int NT = 128;                           // n-tiles of 1024 rows
constexpr int NB = NT * CS;                       // 512 blocks

// workspace layout (bytes)
constexpr size_t OFF_HP  = 0;                                    // hpart [CS][Nv][4] f32 : 8 MiB
constexpr size_t OFF_GP  = OFF_HP  + (size_t)CS * Nv * 16;       // gpart                : 8 MiB
constexpr size_t OFF_HG  = OFF_GP  + (size_t)CS * Nv * 16;       // hg [Nv][8] f32       : 4 MiB
constexpr size_t OFF_BS1 = OFF_HG  + (size_t)Nv * 32;            // [NB][2] f64 (z2, zb)
constexpr size_t OFF_BS2 = OFF_BS1 + (size_t)NB * 2 * 8;         // [NB][8] f64 (Sh, Sh2)
constexpr size_t OFF_GRM = OFF_BS2 + (size_t)NB * 8 * 8;         // [15] f64 (pad 16)
constexpr size_t OFF_CP  = OFF_GRM + 16 * 8;                     // [NT] f64
constexpr size_t OFF_CNT = OFF_CP  + (size_t)NT * 8;             // [1000] u32
}

// ---- P1 ----
__global__ __launch_bounds__(256) void fsq_p1(
    const float* __restrict__ z, const float* __restrict__ W_in,
    const float* __restrict__ W_out, const float* __restrict__ b_out,
    float* __restrict__ hpart, float* __restrict__ gpart,
    double* __restrict__ bs1, double* __restrict__ gram,
    unsigned* __restrict__ counts)
{
    __shared__ double red[15 * 256];
    __shared__ float s_wi[CL][4];
    __shared__ float s_wo[CL][4];
    __shared__ float s_bo[CL];

    const int tid = threadIdx.x;
    const int bid = blockIdx.x;
    const int tile = bid >> 2, cs = bid & 3;
    const int b = tile >> 2;
    const int t0 = (tile & 3) * 1024;
    const int c0 = cs * CL;

    if (bid == 0) {
        for (int i = tid; i < 1000; i += 256) counts[i] = 0;
    }
    if (tid < CL) {
        const int c = c0 + tid;
        const float4 wi = *(const float4*)(W_in + c * 4);
        s_wi[tid][0] = wi.x; s_wi[tid][1] = wi.y; s_wi[tid][2] = wi.z; s_wi[tid][3] = wi.w;
        s_wo[tid][0] = W_out[c];
        s_wo[tid][1] = W_out[512 + c];
        s_wo[tid][2] = W_out[1024 + c];
        s_wo[tid][3] = W_out[1536 + c];
        s_bo[tid] = b_out[c];
    }
    __syncthreads();

    float h[4][4] = {}, g[4][4] = {};
    float z2 = 0.f, zb = 0.f;
    const float* zp = z + ((size_t)b * Cv + c0) * Tv + t0 + tid * 4;

#pragma unroll 4
    for (int i = 0; i < CL; ++i) {
        const float4 zv = *(const float4*)(zp + (size_t)i * Tv);
        const float w0 = s_wi[i][0], w1 = s_wi[i][1], w2 = s_wi[i][2], w3 = s_wi[i][3];
        const float u0 = s_wo[i][0], u1 = s_wo[i][1], u2 = s_wo[i][2], u3 = s_wo[i][3];
        const float bo = s_bo[i];
        const float zr[4] = {zv.x, zv.y, zv.z, zv.w};
#pragma unroll
        for (int j = 0; j < 4; ++j) {
            h[j][0] = fmaf(zr[j], w0, h[j][0]);
            h[j][1] = fmaf(zr[j], w1, h[j][1]);
            h[j][2] = fmaf(zr[j], w2, h[j][2]);
            h[j][3] = fmaf(zr[j], w3, h[j][3]);
            g[j][0] = fmaf(zr[j], u0, g[j][0]);
            g[j][1] = fmaf(zr[j], u1, g[j][1]);
            g[j][2] = fmaf(zr[j], u2, g[j][2]);
            g[j][3] = fmaf(zr[j], u3, g[j][3]);
            z2 = fmaf(zr[j], zr[j], z2);
        }
        zb = fmaf((zr[0] + zr[1]) + (zr[2] + zr[3]), bo, zb);
    }

    const size_t n0 = (size_t)tile * 1024 + (size_t)tid * 4;
    {
        float* hp = hpart + ((size_t)cs * Nv + n0) * 4;
        float* gp = gpart + ((size_t)cs * Nv + n0) * 4;
#pragma unroll
        for (int j = 0; j < 4; ++j) {
            *(float4*)(hp + j * 4) = make_float4(h[j][0], h[j][1], h[j][2], h[j][3]);
            *(float4*)(gp + j * 4) = make_float4(g[j][0], g[j][1], g[j][2], g[j][3]);
        }
    }

    red[tid] = (double)z2;
    red[256 + tid] = (double)zb;
    __syncthreads();
    for (int s = 128; s > 0; s >>= 1) {
        if (tid < s) { red[tid] += red[tid + s]; red[256 + tid] += red[256 + tid + s]; }
        __syncthreads();
    }
    if (tid == 0) { bs1[bid * 2] = red[0]; bs1[bid * 2 + 1] = red[256]; }

    if (bid == NB - 1) {
        // Gram of W_out rows, v = W_out b_out, s0 = |b_out|^2 (data-independent)
        double a[15];
#pragma unroll
        for (int k = 0; k < 15; ++k) a[k] = 0.0;
#pragma unroll
        for (int r = 0; r < 2; ++r) {
            const int c = tid + r * 256;
            const double w0 = (double)W_out[c], w1 = (double)W_out[512 + c];
            const double w2 = (double)W_out[1024 + c], w3 = (double)W_out[1536 + c];
            const double bb = (double)b_out[c];
            a[0] += w0 * w0; a[1] += w0 * w1; a[2] += w0 * w2; a[3] += w0 * w3;
            a[4] += w1 * w1; a[5] += w1 * w2; a[6] += w1 * w3;
            a[7] += w2 * w2; a[8] += w2 * w3; a[9] += w3 * w3;
            a[10] += w0 * bb; a[11] += w1 * bb; a[12] += w2 * bb; a[13] += w3 * bb;
            a[14] += bb * bb;
        }
        __syncthreads();
#pragma unroll
        for (int k = 0; k < 15; ++k) red[k * 256 + tid] = a[k];
        __syncthreads();
        for (int s = 128; s > 0; s >>= 1) {
            if (tid < s) {
#pragma unroll
                for (int k = 0; k < 15; ++k) red[k * 256 + tid] += red[k * 256 + tid + s];
            }
            __syncthreads();
        }
        if (tid == 0) {
#pragma unroll
            for (int k = 0; k < 15; ++k) gram[k] = red[k * 256];
        }
    }
}

// ---- P2: combine c-split partials, BN stats ----
__global__ __launch_bounds__(256) void fsq_p2(
    const float* __restrict__ hpart, const float* __restrict__ gpart,
    const float* __restrict__ b_in, float* __restrict__ hg,
    double* __restrict__ bs2)
{
    __shared__ double red[8 * 256];
    const int tid = threadIdx.x;
    const int bid = blockIdx.x;
    const size_t n = (size_t)bid * 256 + tid;

    const float4 p0 = *(const float4*)(hpart + n * 4);
    const float4 p1 = *(const float4*)(hpart + ((size_t)Nv + n) * 4);
    const float4 p2 = *(const float4*)(hpart + ((size_t)2 * Nv + n) * 4);
    const float4 p3 = *(const float4*)(hpart + ((size_t)3 * Nv + n) * 4);
    double hd[4];
    hd[0] = (((double)p0.x + (double)p1.x) + ((double)p2.x + (double)p3.x)) + (double)b_in[0];
    hd[1] = (((double)p0.y + (double)p1.y) + ((double)p2.y + (double)p3.y)) + (double)b_in[1];
    hd[2] = (((double)p0.z + (double)p1.z) + ((double)p2.z + (double)p3.z)) + (double)b_in[2];
    hd[3] = (((double)p0.w + (double)p1.w) + ((double)p2.w + (double)p3.w)) + (double)b_in[3];

    const float4 q0 = *(const float4*)(gpart + n * 4);
    const float4 q1 = *(const float4*)(gpart + ((size_t)Nv + n) * 4);
    const float4 q2 = *(const float4*)(gpart + ((size_t)2 * Nv + n) * 4);
    const float4 q3 = *(const float4*)(gpart + ((size_t)3 * Nv + n) * 4);
    float gs[4];
    gs[0] = (q0.x + q1.x) + (q2.x + q3.x);
    gs[1] = (q0.y + q1.y) + (q2.y + q3.y);
    gs[2] = (q0.z + q1.z) + (q2.z + q3.z);
    gs[3] = (q0.w + q1.w) + (q2.w + q3.w);

    *(float4*)(hg + n * 8)     = make_float4((float)hd[0], (float)hd[1], (float)hd[2], (float)hd[3]);
    *(float4*)(hg + n * 8 + 4) = make_float4(gs[0], gs[1], gs[2], gs[3]);

#pragma unroll
    for (int e = 0; e < 4; ++e) {
        red[e * 256 + tid] = hd[e];
        red[(4 + e) * 256 + tid] = hd[e] * hd[e];
    }
    __syncthreads();
    for (int s = 128; s > 0; s >>= 1) {
        if (tid < s) {
#pragma unroll
            for (int k = 0; k < 8; ++k) red[k * 256 + tid] += red[k * 256 + tid + s];
        }
        __syncthreads();
    }
    if (tid == 0) {
#pragma unroll
        for (int k = 0; k < 8; ++k) bs2[bid * 8 + k] = red[k * 256];
    }
}

// ---- P3: consts (redundant), quantize, histogram, commit partials, write zhat ----
__global__ __launch_bounds__(256) void fsq_p3(
    const float* __restrict__ hg, const float* __restrict__ W_out,
    const float* __restrict__ b_out, const float* __restrict__ gamma,
    const float* __restrict__ beta, const double* __restrict__ bs2,
    const double* __restrict__ gram, unsigned* __restrict__ counts,
    double* __restrict__ cp, float* __restrict__ out)
{
    __shared__ double red[8 * 256];
    __shared__ float s_wo[CL][4];
    __shared__ float s_bo[CL];
    __shared__ double s_cst[8];
    __shared__ double s_gr[15];

    const int tid = threadIdx.x;
    const int bid = blockIdx.x;
    const int tile = bid >> 2, cs = bid & 3;
    const int b = tile >> 2;
    const int t0 = (tile & 3) * 1024;
    const int c0 = cs * CL;

    if (tid < CL) {
        const int c = c0 + tid;
        s_wo[tid][0] = W_out[c];
        s_wo[tid][1] = W_out[512 + c];
        s_wo[tid][2] = W_out[1024 + c];
        s_wo[tid][3] = W_out[1536 + c];
        s_bo[tid] = b_out[c];
    }
    if (tid < 15) s_gr[tid] = gram[tid];

    // redundant per-block reduce of BN stats (512 x 8 f64)
    {
        const double* r0 = bs2 + (size_t)tid * 8;
        const double* r1 = bs2 + (size_t)(tid + 256) * 8;
        double a[8];
#pragma unroll
        for (int k = 0; k < 8; ++k) a[k] = r0[k] + r1[k];
#pragma unroll
        for (int k = 0; k < 8; ++k) red[k * 256 + tid] = a[k];
        __syncthreads();
        for (int s = 128; s > 0; s >>= 1) {
            if (tid < s) {
#pragma unroll
                for (int k = 0; k < 8; ++k) red[k * 256 + tid] += red[k * 256 + tid + s];
            }
            __syncthreads();
        }
        if (tid == 0) {
            const double Ninv = 1.0 / (double)Nv;
#pragma unroll
            for (int e = 0; e < 4; ++e) {
                const double mu = red[e * 256] * Ninv;
                const double var = red[(4 + e) * 256] * Ninv - mu * mu;
                const double sc = (double)gamma[e] / sqrt(var + 1e-5);
                s_cst[e] = sc;
                s_cst[4 + e] = (double)beta[e] - mu * sc;
            }
        }
        __syncthreads();
    }

    const double sc0 = s_cst[0], sc1 = s_cst[1], sc2 = s_cst[2], sc3 = s_cst[3];
    const double bi0 = s_cst[4], bi1 = s_cst[5], bi2 = s_cst[6], bi3 = s_cst[7];
    constexpr double hl0 = (8.0 - 1.0) * (1.0 - 1e-3) / 2.0;
    constexpr double hl1 = (5.0 - 1.0) * (1.0 - 1e-3) / 2.0;
    const double shift0 = tan(0.5 / hl0);

    const size_t n0 = (size_t)tile * 1024 + (size_t)tid * 4;
    float zn[4][4];
    double qsum = 0.0;
#pragma unroll
    for (int j = 0; j < 4; ++j) {
        const float4 ha = *(const float4*)(hg + (n0 + j) * 8);
        const double hn0 = fma((double)ha.x, sc0, bi0);
        const double hn1 = fma((double)ha.y, sc1, bi1);
        const double hn2 = fma((double)ha.z, sc2, bi2);
        const double hn3 = fma((double)ha.w, sc3, bi3);
        const double r0 = rint(tanh(hn0 + shift0) * hl0 - 0.5);
        const double r1 = rint(tanh(hn1) * hl1);
        const double r2 = rint(tanh(hn2) * hl1);
        const double r3 = rint(tanh(hn3) * hl1);
        const double zd0 = r0 * 0.25, zd1 = r1 * 0.5, zd2 = r2 * 0.5, zd3 = r3 * 0.5;
        zn[j][0] = (float)zd0; zn[j][1] = (float)zd1;
        zn[j][2] = (float)zd2; zn[j][3] = (float)zd3;
        if (cs == 0) {
            const float4 ga = *(const float4*)(hg + (n0 + j) * 8 + 4);
            const int code = ((int)r0 + 4) + ((int)r1 + 2) * 8 + ((int)r2 + 2) * 40
                           + ((int)r3 + 2) * 200;
            atomicAdd(&counts[code], 1u);
            const double cg = zd0 * (double)ga.x + zd1 * (double)ga.y
                            + zd2 * (double)ga.z + zd3 * (double)ga.w;
            double q = s_gr[14]
                     + 2.0 * (zd0 * s_gr[10] + zd1 * s_gr[11] + zd2 * s_gr[12] + zd3 * s_gr[13])
                     + zd0 * zd0 * s_gr[0] + zd1 * zd1 * s_gr[4]
                     + zd2 * zd2 * s_gr[7] + zd3 * zd3 * s_gr[9]
                     + 2.0 * (zd0 * zd1 * s_gr[1] + zd0 * zd2 * s_gr[2] + zd0 * zd3 * s_gr[3]
                            + zd1 * zd2 * s_gr[5] + zd1 * zd3 * s_gr[6] + zd2 * zd3 * s_gr[8]);
            qsum += q - 2.0 * cg;
        }
    }

    if (cs == 0) {
        red[tid] = qsum;
        __syncthreads();
        for (int s = 128; s > 0; s >>= 1) {
            if (tid < s) red[tid] += red[tid + s];
            __syncthreads();
        }
        if (tid == 0) cp[tile] = red[0];
    }

    // write zhat: float4 stores, coalesced over t
    float* op = out + ((size_t)b * Cv + c0) * Tv + t0 + tid * 4;
#pragma unroll 4
    for (int i = 0; i < CL; ++i) {
        const float u0 = s_wo[i][0], u1 = s_wo[i][1], u2 = s_wo[i][2], u3 = s_wo[i][3];
        const float bo = s_bo[i];
        float4 o;
        o.x = fmaf(zn[0][0], u0, fmaf(zn[0][1], u1, fmaf(zn[0][2], u2, fmaf(zn[0][3], u3, bo))));
        o.y = fmaf(zn[1][0], u0, fmaf(zn[1][1], u1, fmaf(zn[1][2], u2, fmaf(zn[1][3], u3, bo))));
        o.z = fmaf(zn[2][0], u0, fmaf(zn[2][1], u1, fmaf(zn[2][2], u2, fmaf(zn[2][3], u3, bo))));
        o.w = fmaf(zn[3][0], u0, fmaf(zn[3][1], u1, fmaf(zn[3][2], u2, fmaf(zn[3][3], u3, bo))));
        *(float4*)(op + (size_t)i * Tv) = o;
    }
}

// ---- P4: finalize ----
__global__ __launch_bounds__(256) void fsq_p4(
    const double* __restrict__ bs1, const double* __restrict__ cp,
    const unsigned* __restrict__ counts, float* __restrict__ out, int out_size)
{
    __shared__ double red[4 * 256];
    const int tid = threadIdx.x;
    double cv = (tid < NT) ? cp[tid] : 0.0;
    const double a2 = bs1[tid * 2] + bs1[(tid + 256) * 2];
    const double ab = bs1[tid * 2 + 1] + bs1[(tid + 256) * 2 + 1];
    double pl = 0.0;
    for (int i = tid; i < 1000; i += 256) {
        const double em = (double)counts[i] / (double)Nv;
        pl += em * log(em + 1e-10);
    }
    red[tid] = cv; red[256 + tid] = a2; red[512 + tid] = ab; red[768 + tid] = pl;
    __syncthreads();
    for (int s = 128; s > 0; s >>= 1) {
        if (tid < s) {
            red[tid] += red[tid + s];
            red[256 + tid] += red[256 + tid + s];
            red[512 + tid] += red[512 + tid + s];
            red[768 + tid] += red[768 + tid + s];
        }
        __syncthreads();
    }
    if (tid == 0) {
        const double commit = (red[256] - 2.0 * red[512] + red[0]) / (double)TOTv;
        out[out_size - 2] = (float)commit;
        out[out_size - 1] = (float)exp(-red[768]);
    }
}

extern "C" void kernel_launch(void* const* d_in, const int* in_sizes, int n_in,
                              void* d_out, int out_size, void* d_ws, size_t ws_size,
                              hipStream_t stream) {
    const float* z     = (const float*)d_in[0];
    const float* W_in  = (const float*)d_in[1];
    const float* b_in  = (const float*)d_in[2];
    const float* gamma = (const float*)d_in[3];
    const float* beta  = (const float*)d_in[4];
    const float* W_out = (const float*)d_in[5];
    const float* b_out = (const float*)d_in[6];
    float* out = (float*)d_out;

    char* ws = (char*)d_ws;
    float*    hpart  = (float*)(ws + OFF_HP);
    float*    gpart  = (float*)(ws + OFF_GP);
    float*    hg     = (float*)(ws + OFF_HG);
    double*   bs1    = (double*)(ws + OFF_BS1);
    double*   bs2    = (double*)(ws + OFF_BS2);
    double*   gram   = (double*)(ws + OFF_GRM);
    double*   cp     = (double*)(ws + OFF_CP);
    unsigned* counts = (unsigned*)(ws + OFF_CNT);

    fsq_p1<<<NB, 256, 0, stream>>>(z, W_in, W_out, b_out, hpart, gpart, bs1, gram, counts);
    fsq_p2<<<NB, 256, 0, stream>>>(hpart, gpart, b_in, hg, bs2);
    fsq_p3<<<NB, 256, 0, stream>>>(hg, W_out, b_out, gamma, beta, bs2, gram, counts, cp, out);
    fsq_p4<<<1, 256, 0, stream>>>(bs1, cp, counts, out, out_size);
}